// Round 12
// baseline (497.974 us; speedup 1.0000x reference)
//
#include <hip/hip_runtime.h>
#include <math.h>

#define NEGINF (-INFINITY)
#define NEGINF_BITS ((int)0xFF800000)

typedef unsigned int u32;
typedef unsigned long long u64;

#define RSTB 32   // rows staged in LDS PER BATCH (2 batches x 32 rows x 1KB = 64 KiB static)

__device__ __forceinline__ int rl_i(int x, int l) {
    return __builtin_amdgcn_readlane(x, l);
}
__device__ __forceinline__ float rl_f(float x, int l) {
    return __int_as_float(__builtin_amdgcn_readlane(__float_as_int(x), l));
}

// One DPP max stage. bound_ctrl=false + old=x: invalid source lanes contribute
// x itself (identity for max).
template <int CTRL>
__device__ __forceinline__ float dppmax(float x) {
    int xi = __float_as_int(x);
    int yi = __builtin_amdgcn_update_dpp(xi, xi, CTRL, 0xf, 0xf, false);
    return fmaxf(x, __int_as_float(yi));
}

// Dual DPP max stage: two INDEPENDENT chains interleaved in program order so
// each chain's dependency gap is filled by the other chain's instructions
// (single in-order wave; this is the whole point of 2-batches-per-wave).
template <int CTRL>
__device__ __forceinline__ void dppmax2(float& a, float& b) {
    int ai = __float_as_int(a), bi = __float_as_int(b);
    int a2 = __builtin_amdgcn_update_dpp(ai, ai, CTRL, 0xf, 0xf, false);
    int b2 = __builtin_amdgcn_update_dpp(bi, bi, CTRL, 0xf, 0xf, false);
    a = fmaxf(a, __int_as_float(a2));
    b = fmaxf(b, __int_as_float(b2));
}

// Wave64 max (single chain) for the rescan path.
__device__ __forceinline__ float wave_max64(float x) {
    x = dppmax<0x111>(x); x = dppmax<0x112>(x); x = dppmax<0x114>(x);
    x = dppmax<0x118>(x); x = dppmax<0x142>(x); x = dppmax<0x143>(x);
    return rl_f(x, 63);
}

// Dual wave argmax over (v, idx) for two independent batches; tie-break lowest
// idx (jnp.argmax first-occurrence). Interleaved 6-stage chains + dual ballot
// tails. Rare multi-holder ties take the slow loop (verified logic, R0-R11).
__device__ __forceinline__ void wave_argmax_dual(float vA, int idxA, float vB, int idxB,
                                                 int& gfA, int& gfB) {
    float xA = vA, xB = vB;
    dppmax2<0x111>(xA, xB); dppmax2<0x112>(xA, xB); dppmax2<0x114>(xA, xB);
    dppmax2<0x118>(xA, xB); dppmax2<0x142>(xA, xB); dppmax2<0x143>(xA, xB);
    const float mvA = rl_f(xA, 63);
    const float mvB = rl_f(xB, 63);
    u64 mA = __ballot(vA == mvA);
    u64 mB = __ballot(vB == mvB);
    int lnA = (int)__builtin_ctzll(mA);
    int lnB = (int)__builtin_ctzll(mB);
    gfA = rl_i(idxA, lnA);
    gfB = rl_i(idxB, lnB);
    u64 rA = mA & (mA - 1);
    u64 rB = mB & (mB - 1);
    if (rA) {                          // wave-uniform, almost never taken
        while (rA) {
            int l2 = (int)__builtin_ctzll(rA); rA &= rA - 1;
            int f2 = rl_i(idxA, l2);
            if (f2 < gfA) gfA = f2;
        }
    }
    if (rB) {
        while (rB) {
            int l2 = (int)__builtin_ctzll(rB); rB &= rB - 1;
            int f2 = rl_i(idxB, l2);
            if (f2 < gfB) gfB = f2;
        }
    }
}

// Joint top-2 wave reduction over a SINGLE ROW's 256 values (rescan path).
// Verified R3-R11, absmax=0.
__device__ __forceinline__ void wave_top2(float lv, int lf, float lv2, int lf2,
                                          float& nv, int& nc, float& nv2, int& nc2) {
    float av = lv, bv = lv2;
#define T2STAGE(CTRL) {                                                        \
        float a2 = __int_as_float(__builtin_amdgcn_update_dpp(                 \
            NEGINF_BITS, __float_as_int(av), CTRL, 0xf, 0xf, false));          \
        float b2 = __int_as_float(__builtin_amdgcn_update_dpp(                 \
            NEGINF_BITS, __float_as_int(bv), CTRL, 0xf, 0xf, false));          \
        float t = fminf(av, a2);                                               \
        av = fmaxf(av, a2);                                                    \
        bv = fmaxf(fmaxf(bv, b2), t); }
    T2STAGE(0x111) T2STAGE(0x112) T2STAGE(0x114) T2STAGE(0x118)
    T2STAGE(0x142) T2STAGE(0x143)
#undef T2STAGE
    nv = rl_f(av, 63);
    float sv = rl_f(bv, 63);

    u64 m1 = __ballot(lv == nv);
    int ln = (int)__builtin_ctzll(m1);
    nc = rl_i(lf, ln);

    nv2 = sv; nc2 = 300;
    if (sv > 0.f) {
        if (sv == nv) {
            float b2v = rl_f(lv2, ln);
            if (b2v == nv) {
                nc2 = rl_i(lf2, ln);
            } else {
                u64 rest = m1 & (m1 - 1);
                int l2 = (int)__builtin_ctzll(rest);
                nc2 = rl_i(lf, l2);
            }
        } else {
            u64 m2 = __ballot(lv == sv || lv2 == sv);
            int l2 = (int)__builtin_ctzll(m2);
            float tl = rl_f(lv, l2);
            nc2 = (tl == sv) ? rl_i(lf, l2) : rl_i(lf2, l2);
        }
    }
}

// TWO independent batches per wave. For each batch, lane l owns rows
// {j*64+l : j=0..3} with the R9-verified top-2 cache:
//   rv/rc  : exact best (value,col) over untaken cols; rc==300 = DEAD.
//   s1v/s1c: exact runner-up, eagerly invalidated; 300 = none.
// Lane l owns taken-bits for cols 4l..4l+3 (colmask).
// The two batches' per-step chains are interleaved (dual argmax in one basic
// block, then bookkeeping A;B, then rare dirty sections A;B) so that one
// chain's dependency/hazard gaps are filled by the other's instructions.
// Rows 0..31 of each batch staged in static LDS (chunk-XOR swizzle, verified).
__global__ __launch_bounds__(64, 1) void greedy_perm_kernel(
        const float* __restrict__ soft, float* __restrict__ out, int ntot) {
    __shared__ float smem[2 * RSTB * 256];        // 64 KiB static
    const int lane = threadIdx.x;
    const int b0 = blockIdx.x * 2;
    const int b1 = (b0 + 1 < ntot) ? (b0 + 1) : b0;   // odd tail: duplicate (benign)
    const float* scA = soft + ((size_t)b0 << 16);
    const float* scB = soft + ((size_t)b1 << 16);
    float* obA = out + ((size_t)b0 << 16);
    float* obB = out + ((size_t)b1 << 16);
    float* smA = smem;
    float* smB = smem + RSTB * 256;

    float rvA[4], s1vA[4], rvB[4], s1vB[4];
    int   rcA[4], s1cA[4], rcB[4], s1cB[4];
#pragma unroll
    for (int j = 0; j < 4; ++j) {
        rvA[j] = NEGINF; rcA[j] = 0; s1vA[j] = NEGINF; s1cA[j] = 300;
        rvB[j] = NEGINF; rcB[j] = 0; s1vB[j] = NEGINF; s1cB[j] = 300;
    }

    const float4 zero4 = make_float4(0.f, 0.f, 0.f, 0.f);

    // ---- init: per-row top-2 scan for BOTH batches (32 loads in flight),
    // ---- fused zero-fill, fused LDS staging of rows 0..31 of each batch ----
    for (int k = 0; k < 64; k += 4) {
        float4 wA[4][4], wB[4][4];
#pragma unroll
        for (int j = 0; j < 4; ++j) {
            const float4* rpA = (const float4*)(scA + (size_t)(j * 64 + lane) * 256);
            const float4* rpB = (const float4*)(scB + (size_t)(j * 64 + lane) * 256);
#pragma unroll
            for (int kk = 0; kk < 4; ++kk) { wA[j][kk] = rpA[k + kk]; wB[j][kk] = rpB[k + kk]; }
        }
#pragma unroll
        for (int j = 0; j < 4; ++j) {
            float4* opA = (float4*)(obA + (size_t)(j * 64 + lane) * 256);
            float4* opB = (float4*)(obB + (size_t)(j * 64 + lane) * 256);
#pragma unroll
            for (int kk = 0; kk < 4; ++kk) { opA[k + kk] = zero4; opB[k + kk] = zero4; }
        }
        if (lane < RSTB) {
            // row `lane` (j=0) of each batch: chunk c stored at slot c^lane ->
            // writes spread across bank groups (verified swizzle, R8/R9).
            float* lpA = &smA[lane << 8];
            float* lpB = &smB[lane << 8];
#pragma unroll
            for (int kk = 0; kk < 4; ++kk) {
                *(float4*)&lpA[((k + kk) ^ lane) << 2] = wA[0][kk];
                *(float4*)&lpB[((k + kk) ^ lane) << 2] = wB[0][kk];
            }
        }
#pragma unroll
        for (int j = 0; j < 4; ++j) {
#pragma unroll
            for (int kk = 0; kk < 4; ++kk) {
                const int bc = 4 * (k + kk);
                const float eA[4] = {wA[j][kk].x, wA[j][kk].y, wA[j][kk].z, wA[j][kk].w};
                const float eB[4] = {wB[j][kk].x, wB[j][kk].y, wB[j][kk].z, wB[j][kk].w};
#pragma unroll
                for (int q = 0; q < 4; ++q) {
                    const int cx = bc + q;
                    {
                        const float x = eA[q];
                        const bool g1 = x > rvA[j];
                        const bool g2 = x > s1vA[j];
                        s1vA[j] = g1 ? rvA[j] : (g2 ? x  : s1vA[j]);
                        s1cA[j] = g1 ? rcA[j] : (g2 ? cx : s1cA[j]);
                        rvA[j]  = g1 ? x  : rvA[j];
                        rcA[j]  = g1 ? cx : rcA[j];
                    }
                    {
                        const float x = eB[q];
                        const bool g1 = x > rvB[j];
                        const bool g2 = x > s1vB[j];
                        s1vB[j] = g1 ? rvB[j] : (g2 ? x  : s1vB[j]);
                        s1cB[j] = g1 ? rcB[j] : (g2 ? cx : s1cB[j]);
                        rvB[j]  = g1 ? x  : rvB[j];
                        rcB[j]  = g1 ? cx : rcB[j];
                    }
                }
            }
        }
    }

    // Drain zero-stores before any 1.0 store can target the same address.
    __threadfence_block();

    u32 cmA = 0, cmB = 0;   // per-lane col-taken bits (cols 4l..4l+3)

    // ---- 256 sequential greedy steps, both batches per iteration ----
    for (int step = 0; step < 256; ++step) {
        // Phase 1: local merges (independent; j-ascending => flat-asc ties)
        float bvA = rvA[0]; int bfA = (lane << 8) | (rcA[0] & 255);
        float bvB = rvB[0]; int bfB = (lane << 8) | (rcB[0] & 255);
#pragma unroll
        for (int j = 1; j < 4; ++j) {
            if (rvA[j] > bvA) { bvA = rvA[j]; bfA = (((j << 6) + lane) << 8) | (rcA[j] & 255); }
            if (rvB[j] > bvB) { bvB = rvB[j]; bfB = (((j << 6) + lane) << 8) | (rcB[j] & 255); }
        }

        // Phase 2+3: interleaved dual reduction + tails
        int gfA, gfB;
        wave_argmax_dual(bvA, bfA, bvB, bfB, gfA, gfB);
        const int rA = gfA >> 8, ccA = gfA & 255;
        const int rB = gfB >> 8, ccB = gfB & 255;

        // Phase 4: one exec-masked region, both stores
        if (lane == 0) { obA[gfA] = 1.0f; obB[gfB] = 1.0f; }

        // Phase 5a: bookkeeping A (kill, colmask, spare inval, dirty flags)
        if (lane == (rA & 63)) {
            const int rj = rA >> 6;
#pragma unroll
            for (int j = 0; j < 4; ++j) if (j == rj) { rvA[j] = NEGINF; rcA[j] = 300; }
        }
        if (lane == (ccA >> 2)) cmA |= 1u << (ccA & 3);
#pragma unroll
        for (int j = 0; j < 4; ++j) if (s1cA[j] == ccA) s1cA[j] = 300;
        bool ddA[4]; bool anydA = false;
#pragma unroll
        for (int j = 0; j < 4; ++j) { ddA[j] = (rcA[j] == ccA); anydA |= ddA[j]; }

        // Phase 5b: bookkeeping B
        if (lane == (rB & 63)) {
            const int rj = rB >> 6;
#pragma unroll
            for (int j = 0; j < 4; ++j) if (j == rj) { rvB[j] = NEGINF; rcB[j] = 300; }
        }
        if (lane == (ccB >> 2)) cmB |= 1u << (ccB & 3);
#pragma unroll
        for (int j = 0; j < 4; ++j) if (s1cB[j] == ccB) s1cB[j] = 300;
        bool ddB[4]; bool anydB = false;
#pragma unroll
        for (int j = 0; j < 4; ++j) { ddB[j] = (rcB[j] == ccB); anydB |= ddB[j]; }

        // Phase 6a: dirty section A (R9-verified logic)
        if (__ballot(anydA)) {
#pragma unroll
            for (int j = 0; j < 4; ++j) {
                const bool need = ddA[j] && (s1cA[j] == 300);
                if (ddA[j] && !need) {           // exact in-register advance
                    rvA[j] = s1vA[j]; rcA[j] = s1cA[j];
                    s1vA[j] = NEGINF; s1cA[j] = 300;
                }
                u64 m = __ballot(need);
                while (m) {
                    const int ln = (int)__builtin_ctzll(m); m &= m - 1;
                    const int row = (j << 6) + ln;
                    float4 w = (row < RSTB)
                        ? *(const float4*)&smA[(row << 8) | (((lane ^ ln) & 63) << 2)]
                        : *(const float4*)(scA + ((size_t)row << 8) + (lane << 2));
                    const float q0 = (cmA & 1u) ? NEGINF : w.x;
                    const float q1 = (cmA & 2u) ? NEGINF : w.y;
                    const float q2 = (cmA & 4u) ? NEGINF : w.z;
                    const float q3 = (cmA & 8u) ? NEGINF : w.w;
                    const int cb = lane << 2;
                    float lv = q0; int lf = cb;
                    float lv2 = NEGINF; int lf2 = cb;
                    {
                        bool g1 = q1 > lv, g2 = q1 > lv2;
                        lv2 = g1 ? lv : (g2 ? q1 : lv2); lf2 = g1 ? lf : (g2 ? cb + 1 : lf2);
                        lv  = g1 ? q1 : lv;              lf  = g1 ? cb + 1 : lf;
                        g1 = q2 > lv; g2 = q2 > lv2;
                        lv2 = g1 ? lv : (g2 ? q2 : lv2); lf2 = g1 ? lf : (g2 ? cb + 2 : lf2);
                        lv  = g1 ? q2 : lv;              lf  = g1 ? cb + 2 : lf;
                        g1 = q3 > lv; g2 = q3 > lv2;
                        lv2 = g1 ? lv : (g2 ? q3 : lv2); lf2 = g1 ? lf : (g2 ? cb + 3 : lf2);
                        lv  = g1 ? q3 : lv;              lf  = g1 ? cb + 3 : lf;
                    }
                    float nv, nv2; int nc, nc2;
                    wave_top2(lv, lf, lv2, lf2, nv, nc, nv2, nc2);
                    if (lane == ln) {
#pragma unroll
                        for (int jj = 0; jj < 4; ++jj) if (jj == j) {
                            rvA[jj] = nv; rcA[jj] = nc;
                            s1vA[jj] = nv2; s1cA[jj] = nc2;   // 300 if none
                        }
                    }
                }
            }
        }

        // Phase 6b: dirty section B
        if (__ballot(anydB)) {
#pragma unroll
            for (int j = 0; j < 4; ++j) {
                const bool need = ddB[j] && (s1cB[j] == 300);
                if (ddB[j] && !need) {
                    rvB[j] = s1vB[j]; rcB[j] = s1cB[j];
                    s1vB[j] = NEGINF; s1cB[j] = 300;
                }
                u64 m = __ballot(need);
                while (m) {
                    const int ln = (int)__builtin_ctzll(m); m &= m - 1;
                    const int row = (j << 6) + ln;
                    float4 w = (row < RSTB)
                        ? *(const float4*)&smB[(row << 8) | (((lane ^ ln) & 63) << 2)]
                        : *(const float4*)(scB + ((size_t)row << 8) + (lane << 2));
                    const float q0 = (cmB & 1u) ? NEGINF : w.x;
                    const float q1 = (cmB & 2u) ? NEGINF : w.y;
                    const float q2 = (cmB & 4u) ? NEGINF : w.z;
                    const float q3 = (cmB & 8u) ? NEGINF : w.w;
                    const int cb = lane << 2;
                    float lv = q0; int lf = cb;
                    float lv2 = NEGINF; int lf2 = cb;
                    {
                        bool g1 = q1 > lv, g2 = q1 > lv2;
                        lv2 = g1 ? lv : (g2 ? q1 : lv2); lf2 = g1 ? lf : (g2 ? cb + 1 : lf2);
                        lv  = g1 ? q1 : lv;              lf  = g1 ? cb + 1 : lf;
                        g1 = q2 > lv; g2 = q2 > lv2;
                        lv2 = g1 ? lv : (g2 ? q2 : lv2); lf2 = g1 ? lf : (g2 ? cb + 2 : lf2);
                        lv  = g1 ? q2 : lv;              lf  = g1 ? cb + 2 : lf;
                        g1 = q3 > lv; g2 = q3 > lv2;
                        lv2 = g1 ? lv : (g2 ? q3 : lv2); lf2 = g1 ? lf : (g2 ? cb + 3 : lf2);
                        lv  = g1 ? q3 : lv;              lf  = g1 ? cb + 3 : lf;
                    }
                    float nv, nv2; int nc, nc2;
                    wave_top2(lv, lf, lv2, lf2, nv, nc, nv2, nc2);
                    if (lane == ln) {
#pragma unroll
                        for (int jj = 0; jj < 4; ++jj) if (jj == j) {
                            rvB[jj] = nv; rcB[jj] = nc;
                            s1vB[jj] = nv2; s1cB[jj] = nc2;
                        }
                    }
                }
            }
        }
    }
}

extern "C" void kernel_launch(void* const* d_in, const int* in_sizes, int n_in,
                              void* d_out, int out_size, void* d_ws, size_t ws_size,
                              hipStream_t stream) {
    const float* soft = (const float*)d_in[0];
    float* out = (float*)d_out;
    const int n_batches = in_sizes[0] >> 16;   // elements / (256*256)
    const int n_blocks = (n_batches + 1) >> 1; // 2 batches per wave

    greedy_perm_kernel<<<n_blocks, 64, 0, stream>>>(soft, out, n_batches);
}